// Round 1
// baseline (6684.341 us; speedup 1.0000x reference)
//
#include <hip/hip_runtime.h>
#include <cmath>

// Shapes (fixed by the problem)
#define Bb   4
#define Tt   288      // NV(256) + NQ(32)
#define Dd   1024
#define DIi  2048
#define HH   32
#define PP   64
#define NNs  128
#define PROJ 4384     // 2*DI + 2*N + H
#define NLl  12
#define EE   1536

// ---------------- block reduction helper ----------------
__device__ inline float block_reduce_sum(float v, float* lds) {
#pragma unroll
  for (int d = 32; d > 0; d >>= 1) v += __shfl_down(v, d, 64);
  int lane = threadIdx.x & 63;
  int w = threadIdx.x >> 6;
  if (lane == 0) lds[w] = v;
  __syncthreads();
  if (threadIdx.x == 0) {
    float s = lds[0];
    int nw = blockDim.x >> 6;
    for (int i = 1; i < nw; i++) s += lds[i];
    lds[0] = s;
  }
  __syncthreads();
  return lds[0];
}

// ---------------- general tiled fp32 GEMM ----------------
// C[orow, :] = A[r, :K] @ W[K, N] (+bias) (+res), orow = (r/rows_per_b)*T_total + r%rows_per_b + t_off
// 64x64 tile, BK=16, 256 threads, 4x4 microtile. Bounds-checked on M and N.
__global__ __launch_bounds__(256) void gemm_k(
    const float* __restrict__ A, const float* __restrict__ W,
    const float* __restrict__ bias, const float* __restrict__ res,
    float* __restrict__ C, int M, int N, int K,
    int rows_per_b, int T_total, int t_off)
{
  __shared__ float As[16][64];   // transposed: As[k][m]
  __shared__ float Ws[16][64];   // natural:    Ws[k][n]
  const int tid = threadIdx.x;
  const int tx = tid & 15;
  const int ty = tid >> 4;
  const int m0 = blockIdx.y * 64;
  const int n0 = blockIdx.x * 64;
  float acc[4][4] = {};
  const int ar = tid >> 2;          // 0..63
  const int ac = (tid & 3) << 2;    // 0,4,8,12
  const int wr = tid >> 4;          // 0..15
  const int wc = (tid & 15) << 2;   // 0..60

  for (int k0 = 0; k0 < K; k0 += 16) {
    float4 av = {0.f, 0.f, 0.f, 0.f};
    int gr = m0 + ar;
    if (gr < M) av = *(const float4*)&A[(size_t)gr * K + k0 + ac];
    As[ac + 0][ar] = av.x; As[ac + 1][ar] = av.y;
    As[ac + 2][ar] = av.z; As[ac + 3][ar] = av.w;

    float4 wv = {0.f, 0.f, 0.f, 0.f};
    int gc = n0 + wc;
    const float* wp = &W[(size_t)(k0 + wr) * N + gc];
    if (gc + 3 < N) {
      wv = *(const float4*)wp;
    } else {
      if (gc + 0 < N) wv.x = wp[0];
      if (gc + 1 < N) wv.y = wp[1];
      if (gc + 2 < N) wv.z = wp[2];
    }
    *(float4*)&Ws[wr][wc] = wv;
    __syncthreads();

#pragma unroll
    for (int kk = 0; kk < 16; kk++) {
      float4 a4 = *(const float4*)&As[kk][ty << 2];
      float4 b4 = *(const float4*)&Ws[kk][tx << 2];
      float a[4] = {a4.x, a4.y, a4.z, a4.w};
      float b[4] = {b4.x, b4.y, b4.z, b4.w};
#pragma unroll
      for (int i = 0; i < 4; i++)
#pragma unroll
        for (int j = 0; j < 4; j++)
          acc[i][j] = fmaf(a[i], b[j], acc[i][j]);
    }
    __syncthreads();
  }

#pragma unroll
  for (int i = 0; i < 4; i++) {
    int gr = m0 + (ty << 2) + i;
    if (gr >= M) continue;
    int bbv = gr / rows_per_b;
    int tt = gr - bbv * rows_per_b;
    size_t orow = (size_t)bbv * T_total + tt + t_off;
#pragma unroll
    for (int j = 0; j < 4; j++) {
      int gc = n0 + (tx << 2) + j;
      if (gc >= N) continue;
      float v = acc[i][j];
      if (bias) v += bias[gc];
      if (res)  v += res[orow * (size_t)N + gc];
      C[orow * (size_t)N + gc] = v;
    }
  }
}

// ---------------- RMSNorm over rows of length 1024 ----------------
__global__ __launch_bounds__(256) void rmsnorm_k(
    const float* __restrict__ x, const float* __restrict__ w, float* __restrict__ out)
{
  __shared__ float lds[8];
  const int row = blockIdx.x;
  const float* xr = x + (size_t)row * Dd;
  float4 v = *(const float4*)&xr[threadIdx.x << 2];
  float ss = v.x * v.x + v.y * v.y + v.z * v.z + v.w * v.w;
  ss = block_reduce_sum(ss, lds);
  float sc = rsqrtf(ss * (1.f / Dd) + 1e-5f);
  float4 wv = *(const float4*)&w[threadIdx.x << 2];
  float4 o = {v.x * sc * wv.x, v.y * sc * wv.y, v.z * sc * wv.z, v.w * sc * wv.w};
  *(float4*)&out[(size_t)row * Dd + (threadIdx.x << 2)] = o;
}

// ---------------- dt = softplus(proj_dt + bias), da = exp(dt*A) ----------------
__global__ void dtda_k(const float* __restrict__ proj, const float* __restrict__ dt_bias,
                       const float* __restrict__ A_log, float* __restrict__ dtb,
                       float* __restrict__ dab)
{
  int idx = blockIdx.x * 256 + threadIdx.x;   // over (b*T) * H
  if (idx >= Bb * Tt * HH) return;
  int row = idx >> 5;
  int h = idx & 31;
  float v = proj[(size_t)row * PROJ + 2 * DIi + 2 * NNs + h] + dt_bias[h];
  float dt = (v > 20.f) ? v : log1pf(expf(v));
  float A = -expf(A_log[h]);
  dtb[idx] = dt;
  dab[idx] = expf(dt * A);
}

// ---------------- SSD scan ----------------
// one wave owns (b, h, 4 p-rows); lane = (p_local in [0,4)) x (n-chunk of 8)
// state h[p][n] and u_prev kept in registers; sequential over T; no barriers.
__global__ __launch_bounds__(256) void scan_k(
    const float* __restrict__ proj, const float* __restrict__ dtb,
    const float* __restrict__ dab, const float* __restrict__ Dssm,
    float* __restrict__ ybuf)
{
  const int gw = blockIdx.x * 4 + (threadIdx.x >> 6);   // 0..2047
  const int lane = threadIdx.x & 63;
  const int pg = gw & 15;
  const int h = (gw >> 4) & 31;
  const int b = gw >> 9;
  const int p_local = lane & 3;
  const int chunk = lane >> 2;            // 0..15
  const int p = (pg << 2) + p_local;
  const int n0 = chunk << 3;
  const float Ds = Dssm[h];
  const float* prow = proj + (size_t)b * Tt * PROJ;
  const int xoff = DIi + h * PP + p;
  const int boff = 2 * DIi + n0;
  const int coff = 2 * DIi + NNs + n0;

  float hs[8] = {0, 0, 0, 0, 0, 0, 0, 0};
  float up[8] = {0, 0, 0, 0, 0, 0, 0, 0};  // u_{t-1}: the shift() terms

  float4 B0, B1, C0, C1; float xv, dtv, dav;
  {
    const float* r0 = prow;
    xv = r0[xoff];
    B0 = *(const float4*)&r0[boff];
    B1 = *(const float4*)&r0[boff + 4];
    C0 = *(const float4*)&r0[coff];
    C1 = *(const float4*)&r0[coff + 4];
    int bt = (b * Tt) * HH + h;
    dtv = dtb[bt]; dav = dab[bt];
  }
  for (int t = 0; t < Tt; t++) {
    float4 nB0 = {0,0,0,0}, nB1 = {0,0,0,0}, nC0 = {0,0,0,0}, nC1 = {0,0,0,0};
    float nx = 0.f, ndt = 0.f, nda = 0.f;
    if (t + 1 < Tt) {   // prefetch next step while computing this one
      const float* r1 = prow + (size_t)(t + 1) * PROJ;
      nx = r1[xoff];
      nB0 = *(const float4*)&r1[boff];
      nB1 = *(const float4*)&r1[boff + 4];
      nC0 = *(const float4*)&r1[coff];
      nC1 = *(const float4*)&r1[coff + 4];
      int bt = (b * Tt + t + 1) * HH + h;
      ndt = dtb[bt]; nda = dab[bt];
    }
    float dtx = dtv * xv;
    float s1 = 0.5f * dav;   // alpha*da
    float Ba[8] = {B0.x, B0.y, B0.z, B0.w, B1.x, B1.y, B1.z, B1.w};
    float Ca[8] = {C0.x, C0.y, C0.z, C0.w, C1.x, C1.y, C1.z, C1.w};
    float yp = 0.f;
#pragma unroll
    for (int e = 0; e < 8; e++) {
      float u = dtx * Ba[e];
      float inner = fmaf(s1, up[e], 0.5f * u);   // alpha*da*u_prev + (1-alpha)*u
      hs[e] = fmaf(dav, hs[e], inner);           // h = da*h + inner
      yp = fmaf(hs[e], Ca[e], yp);
      up[e] = u;
    }
    // reduce over the 16 lanes sharing p (lane stride 4)
    yp += __shfl_down(yp, 32, 64);
    yp += __shfl_down(yp, 16, 64);
    yp += __shfl_down(yp, 8, 64);
    yp += __shfl_down(yp, 4, 64);
    if (lane < 4) {   // lane == p_local, chunk 0
      ybuf[((size_t)b * Tt + t) * DIi + h * PP + (pg << 2) + lane] = yp + Ds * xv;
    }
    xv = nx; dtv = ndt; dav = nda;
    B0 = nB0; B1 = nB1; C0 = nC0; C1 = nC1;
  }
}

// ---------------- fused silu-gate + RMSNorm over DI=2048, in-place on ybuf ----------------
__global__ __launch_bounds__(256) void gate_norm_k(
    float* __restrict__ ybuf, const float* __restrict__ proj, const float* __restrict__ gw)
{
  __shared__ float lds[8];
  const int row = blockIdx.x;
  float* yr = ybuf + (size_t)row * DIi;
  const float* zr = proj + (size_t)row * PROJ;   // z = cols [0, 2048)
  float g[8];
  float ss = 0.f;
#pragma unroll
  for (int e = 0; e < 8; e++) {
    int idx = (e << 8) + threadIdx.x;
    float z = zr[idx];
    float y = yr[idx];
    float s = z / (1.f + expf(-z));   // silu
    float gv = y * s;
    g[e] = gv;
    ss += gv * gv;
  }
  ss = block_reduce_sum(ss, lds);
  float sc = rsqrtf(ss * (1.f / DIi) + 1e-5f);
#pragma unroll
  for (int e = 0; e < 8; e++) {
    int idx = (e << 8) + threadIdx.x;
    yr[idx] = g[e] * sc * gw[idx];
  }
}

// ---------------- mean over T ----------------
__global__ void pool_k(const float* __restrict__ xin, float* __restrict__ pooled) {
  int b = blockIdx.x;
  int d = blockIdx.y * 256 + threadIdx.x;
  const float* base = xin + (size_t)b * Tt * Dd + d;
  float s = 0.f;
  for (int t = 0; t < Tt; t++) s += base[(size_t)t * Dd];
  pooled[b * Dd + d] = s * (1.f / Tt);
}

// ---------------- L2-normalize rows of (4, 1536), in place ----------------
__global__ __launch_bounds__(256) void l2norm_k(float* __restrict__ out) {
  __shared__ float lds[8];
  const int row = blockIdx.x;
  float* r = out + (size_t)row * EE;
  float v[6];
  float ss = 0.f;
#pragma unroll
  for (int e = 0; e < 6; e++) {
    v[e] = r[(e << 8) + threadIdx.x];
    ss += v[e] * v[e];
  }
  ss = block_reduce_sum(ss, lds);
  float sc = 1.f / fmaxf(sqrtf(ss), 1e-12f);
#pragma unroll
  for (int e = 0; e < 6; e++) r[(e << 8) + threadIdx.x] = v[e] * sc;
}

// ---------------- launch ----------------
extern "C" void kernel_launch(void* const* d_in, const int* in_sizes, int n_in,
                              void* d_out, int out_size, void* d_ws, size_t ws_size,
                              hipStream_t stream) {
  (void)in_sizes; (void)n_in; (void)out_size; (void)ws_size;
  const float* visual   = (const float*)d_in[0];
  const float* query    = (const float*)d_in[1];
  const float* vis_w    = (const float*)d_in[2];
  const float* vis_b    = (const float*)d_in[3];
  const float* qry_w    = (const float*)d_in[4];
  const float* qry_b    = (const float*)d_in[5];
  const float* norm_ws  = (const float*)d_in[6];
  const float* in_ws    = (const float*)d_in[7];
  const float* dt_biases= (const float*)d_in[8];
  const float* A_logs   = (const float*)d_in[9];
  const float* D_ssm    = (const float*)d_in[10];
  const float* gnorm_ws = (const float*)d_in[11];
  const float* out_ws   = (const float*)d_in[12];
  const float* norm_f_w = (const float*)d_in[13];
  const float* head_w   = (const float*)d_in[14];
  const float* head_b   = (const float*)d_in[15];
  float* out = (float*)d_out;

  // workspace layout (floats): total ~9.85M floats = ~39.4 MB
  float* ws = (float*)d_ws;
  float* hidden = ws;                       // 1152*1024
  float* xin    = hidden + 1179648;         // 1152*1024
  float* proj   = xin + 1179648;            // 1152*4384
  float* ybuf   = proj + 5050368;           // 1152*2048
  float* dtb    = ybuf + 2359296;           // 1152*32
  float* dab    = dtb + 36864;              // 1152*32
  float* pooled = dab + 36864;              // 4*1024

  dim3 blk(256);

  // hidden = concat(vis @ vis_w + b, qry @ qry_w + b) along T
  gemm_k<<<dim3(16, 16), blk, 0, stream>>>(visual, vis_w, vis_b, nullptr, hidden,
                                           1024, 1024, 1024, 256, Tt, 0);
  gemm_k<<<dim3(16, 2), blk, 0, stream>>>(query, qry_w, qry_b, nullptr, hidden,
                                          128, 1024, 1024, 32, Tt, 256);

  for (int i = 0; i < NLl; i++) {
    rmsnorm_k<<<Bb * Tt, blk, 0, stream>>>(hidden, norm_ws + i * Dd, xin);
    gemm_k<<<dim3(69, 18), blk, 0, stream>>>(xin, in_ws + (size_t)i * Dd * PROJ,
                                             nullptr, nullptr, proj,
                                             Bb * Tt, PROJ, Dd, Bb * Tt, 0, 0);
    dtda_k<<<144, blk, 0, stream>>>(proj, dt_biases + i * HH, A_logs + i * HH, dtb, dab);
    scan_k<<<512, blk, 0, stream>>>(proj, dtb, dab, D_ssm + i * HH, ybuf);
    gate_norm_k<<<Bb * Tt, blk, 0, stream>>>(ybuf, proj, gnorm_ws + i * DIi);
    gemm_k<<<dim3(16, 18), blk, 0, stream>>>(ybuf, out_ws + (size_t)i * DIi * Dd,
                                             nullptr, hidden, hidden,
                                             Bb * Tt, Dd, DIi, Bb * Tt, 0, 0);
  }

  rmsnorm_k<<<Bb * Tt, blk, 0, stream>>>(hidden, norm_f_w, xin);
  pool_k<<<dim3(Bb, 4), blk, 0, stream>>>(xin, pooled);
  gemm_k<<<dim3(24, 1), blk, 0, stream>>>(pooled, head_w, head_b, nullptr, out,
                                          Bb, EE, Dd, Bb, 0, 0);
  l2norm_k<<<Bb, blk, 0, stream>>>(out);
}

// Round 3
// 3373.969 us; speedup vs baseline: 1.9812x; 1.9812x over previous
//
#include <hip/hip_runtime.h>
#include <cmath>

// Shapes (fixed by the problem)
#define Bb   4
#define Tt   288      // NV(256) + NQ(32)
#define Dd   1024
#define DIi  2048
#define HH   32
#define PP   64
#define NNs  128
#define PROJ  4384    // 2*DI + 2*N + H (logical)
#define PROJP 4480    // padded to 35*128 for MFMA tiles
#define NLl  12
#define EE   1536

typedef __bf16 bf16x8 __attribute__((ext_vector_type(8)));
typedef float f32x4 __attribute__((ext_vector_type(4)));

__device__ __forceinline__ unsigned short f2bf(float v) {
  __bf16 b = (__bf16)v;
  return __builtin_bit_cast(unsigned short, b);
}
__device__ __forceinline__ float bf2f(unsigned short u) {
  unsigned int x = ((unsigned int)u) << 16;
  return __builtin_bit_cast(float, x);
}
// split fp32 -> (hi, lo) bf16 pair: v ~= hi + lo to ~16 mantissa bits
__device__ __forceinline__ void split2(float v, unsigned short& h, unsigned short& l) {
  h = f2bf(v);
  l = f2bf(v - bf2f(h));
}

// async global->LDS, 16B per lane (lane-linear LDS layout required)
__device__ __forceinline__ void async16(const void* g, void* l) {
  __builtin_amdgcn_global_load_lds(
      (const __attribute__((address_space(1))) unsigned int*)g,
      (__attribute__((address_space(3))) unsigned int*)l, 16, 0, 0);
}

// ---------------- block reduction helper ----------------
__device__ inline float block_reduce_sum(float v, float* lds) {
#pragma unroll
  for (int d = 32; d > 0; d >>= 1) v += __shfl_down(v, d, 64);
  int lane = threadIdx.x & 63;
  int w = threadIdx.x >> 6;
  if (lane == 0) lds[w] = v;
  __syncthreads();
  if (threadIdx.x == 0) {
    float s = lds[0];
    int nw = blockDim.x >> 6;
    for (int i = 1; i < nw; i++) s += lds[i];
    lds[0] = s;
  }
  __syncthreads();
  return lds[0];
}

// ---------------- fp32 -> bf16 hi/lo (activations) ----------------
__global__ __launch_bounds__(256) void cvt_act2_k(const float* __restrict__ x,
                                                  unsigned short* __restrict__ oh,
                                                  unsigned short* __restrict__ ol, int n) {
  int idx = (blockIdx.x * 256 + threadIdx.x) * 4;
  if (idx >= n) return;
  float4 v = *(const float4*)&x[idx];
  ushort4 h, l;
  split2(v.x, h.x, l.x); split2(v.y, h.y, l.y);
  split2(v.z, h.z, l.z); split2(v.w, h.w, l.w);
  *(ushort4*)&oh[idx] = h;
  *(ushort4*)&ol[idx] = l;
}

// ---------------- W fp32 [K][N] -> Wt hi/lo bf16 [Npad][K] (transpose+split+pad) ----------------
__global__ __launch_bounds__(256) void cvt_tr2_k(const float* __restrict__ W,
                                                 unsigned short* __restrict__ Wth,
                                                 unsigned short* __restrict__ Wtl,
                                                 int K, int N) {
  __shared__ float tile[32][33];
  const int n0 = blockIdx.x * 32, k0 = blockIdx.y * 32;
  const int c = threadIdx.x & 31;
  const int r0 = threadIdx.x >> 5;   // 0..7
#pragma unroll
  for (int j = 0; j < 4; j++) {
    int r = r0 + j * 8;
    int n = n0 + c;
    tile[r][c] = (n < N) ? W[(size_t)(k0 + r) * N + n] : 0.f;
  }
  __syncthreads();
  const int nl = threadIdx.x >> 3;        // 0..31
  const int kl = (threadIdx.x & 7) * 4;   // 0..28
  ushort4 h, l;
  split2(tile[kl + 0][nl], h.x, l.x);
  split2(tile[kl + 1][nl], h.y, l.y);
  split2(tile[kl + 2][nl], h.z, l.z);
  split2(tile[kl + 3][nl], h.w, l.w);
  size_t o = (size_t)(n0 + nl) * K + k0 + kl;
  *(ushort4*)&Wth[o] = h;
  *(ushort4*)&Wtl[o] = l;
}

// ---------------- split-bf16 MFMA GEMM, B^T, 3-term (hi*hi + hi*lo + lo*hi) ----------------
// C[orow,:] = A[m,:K] @ Wt[n,:K]^T (+bias) (+res); M,N multiples of BM,BN; K mult of 32.
template<int BM, int BN>
__global__ __launch_bounds__(256) void gemm3_k(
    const unsigned short* __restrict__ Ah, const unsigned short* __restrict__ Al,
    const unsigned short* __restrict__ Wh, const unsigned short* __restrict__ Wl,
    const float* __restrict__ bias, const float* __restrict__ res,
    float* __restrict__ C, int M, int N, int K,
    int rows_per_b, int T_total, int t_off)
{
  constexpr int FM = BM / 32;   // frags per wave (m)
  constexpr int FN = BN / 32;   // frags per wave (n)
  __shared__ __align__(16) unsigned short Ash[BM * 32];
  __shared__ __align__(16) unsigned short Asl[BM * 32];
  __shared__ __align__(16) unsigned short Bsh[BN * 32];
  __shared__ __align__(16) unsigned short Bsl[BN * 32];
  const int tid = threadIdx.x;
  const int lane = tid & 63;
  const int wm = (tid >> 6) >> 1;
  const int wn = (tid >> 6) & 1;
  const int m0 = blockIdx.y * BM;
  const int n0 = blockIdx.x * BN;
  const int lrow = lane & 15;
  const int lkb = (lane >> 4) * 8;   // k-element offset within tile

  f32x4 acc[FM][FN];
#pragma unroll
  for (int i = 0; i < FM; i++)
#pragma unroll
    for (int j = 0; j < FN; j++) acc[i][j] = (f32x4)0.0f;

  for (int k0 = 0; k0 < K; k0 += 32) {
#pragma unroll
    for (int c = 0; c < BM / 64; c++) {
      int o = (c * 256 + tid) * 16;    // byte offset (row-major [BM][32] bf16 = 64B/row)
      int row = o >> 6;
      int colb = o & 63;
      size_t gb = ((size_t)(m0 + row) * K + k0) * 2 + colb;
      async16((const char*)Ah + gb, (char*)Ash + o);
      async16((const char*)Al + gb, (char*)Asl + o);
    }
#pragma unroll
    for (int c = 0; c < BN / 64; c++) {
      int o = (c * 256 + tid) * 16;
      int row = o >> 6;
      int colb = o & 63;
      size_t gb = ((size_t)(n0 + row) * K + k0) * 2 + colb;
      async16((const char*)Wh + gb, (char*)Bsh + o);
      async16((const char*)Wl + gb, (char*)Bsl + o);
    }
    __syncthreads();   // drains vmcnt (global_load_lds) + barrier

    bf16x8 ah[FM], al[FM], bh[FN], bl[FN];
#pragma unroll
    for (int i = 0; i < FM; i++) {
      int off = (wm * (FM * 16) + i * 16 + lrow) * 32 + lkb;
      ah[i] = *(const bf16x8*)&Ash[off];
      al[i] = *(const bf16x8*)&Asl[off];
    }
#pragma unroll
    for (int j = 0; j < FN; j++) {
      int off = (wn * (FN * 16) + j * 16 + lrow) * 32 + lkb;
      bh[j] = *(const bf16x8*)&Bsh[off];
      bl[j] = *(const bf16x8*)&Bsl[off];
    }
#pragma unroll
    for (int i = 0; i < FM; i++)
#pragma unroll
      for (int j = 0; j < FN; j++) {
        acc[i][j] = __builtin_amdgcn_mfma_f32_16x16x32_bf16(ah[i], bh[j], acc[i][j], 0, 0, 0);
        acc[i][j] = __builtin_amdgcn_mfma_f32_16x16x32_bf16(ah[i], bl[j], acc[i][j], 0, 0, 0);
        acc[i][j] = __builtin_amdgcn_mfma_f32_16x16x32_bf16(al[i], bh[j], acc[i][j], 0, 0, 0);
      }
    __syncthreads();
  }

  const int erow = (lane >> 4) * 4;
#pragma unroll
  for (int i = 0; i < FM; i++) {
    int mbase = m0 + wm * (FM * 16) + i * 16 + erow;
#pragma unroll
    for (int j = 0; j < FN; j++) {
      int ncol = n0 + wn * (FN * 16) + j * 16 + lrow;
      float bv = bias ? bias[ncol] : 0.f;
#pragma unroll
      for (int e = 0; e < 4; e++) {
        int m = mbase + e;
        size_t orow;
        if (T_total) {
          int bbv = m / rows_per_b;
          orow = (size_t)bbv * T_total + (m - bbv * rows_per_b) + t_off;
        } else {
          orow = (size_t)m;
        }
        float v = acc[i][j][e] + bv;
        if (res) v += res[orow * N + ncol];
        C[orow * N + ncol] = v;
      }
    }
  }
}

// ---------------- general tiled fp32 GEMM (tiny head matmul only) ----------------
__global__ __launch_bounds__(256) void gemm_k(
    const float* __restrict__ A, const float* __restrict__ W,
    const float* __restrict__ bias, const float* __restrict__ res,
    float* __restrict__ C, int M, int N, int K,
    int rows_per_b, int T_total, int t_off)
{
  __shared__ float As[16][64];
  __shared__ float Ws[16][64];
  const int tid = threadIdx.x;
  const int tx = tid & 15;
  const int ty = tid >> 4;
  const int m0 = blockIdx.y * 64;
  const int n0 = blockIdx.x * 64;
  float acc[4][4] = {};
  const int ar = tid >> 2;
  const int ac = (tid & 3) << 2;
  const int wr = tid >> 4;
  const int wc = (tid & 15) << 2;

  for (int k0 = 0; k0 < K; k0 += 16) {
    float4 av = {0.f, 0.f, 0.f, 0.f};
    int gr = m0 + ar;
    if (gr < M) av = *(const float4*)&A[(size_t)gr * K + k0 + ac];
    As[ac + 0][ar] = av.x; As[ac + 1][ar] = av.y;
    As[ac + 2][ar] = av.z; As[ac + 3][ar] = av.w;

    float4 wv = {0.f, 0.f, 0.f, 0.f};
    int gc = n0 + wc;
    const float* wp = &W[(size_t)(k0 + wr) * N + gc];
    if (gc + 3 < N) {
      wv = *(const float4*)wp;
    } else {
      if (gc + 0 < N) wv.x = wp[0];
      if (gc + 1 < N) wv.y = wp[1];
      if (gc + 2 < N) wv.z = wp[2];
    }
    *(float4*)&Ws[wr][wc] = wv;
    __syncthreads();
#pragma unroll
    for (int kk = 0; kk < 16; kk++) {
      float4 a4 = *(const float4*)&As[kk][ty << 2];
      float4 b4 = *(const float4*)&Ws[kk][tx << 2];
      float a[4] = {a4.x, a4.y, a4.z, a4.w};
      float b[4] = {b4.x, b4.y, b4.z, b4.w};
#pragma unroll
      for (int i = 0; i < 4; i++)
#pragma unroll
        for (int j = 0; j < 4; j++)
          acc[i][j] = fmaf(a[i], b[j], acc[i][j]);
    }
    __syncthreads();
  }
#pragma unroll
  for (int i = 0; i < 4; i++) {
    int gr = m0 + (ty << 2) + i;
    if (gr >= M) continue;
    int bbv = gr / rows_per_b;
    int tt = gr - bbv * rows_per_b;
    size_t orow = (size_t)bbv * T_total + tt + t_off;
#pragma unroll
    for (int j = 0; j < 4; j++) {
      int gc = n0 + (tx << 2) + j;
      if (gc >= N) continue;
      float v = acc[i][j];
      if (bias) v += bias[gc];
      if (res)  v += res[orow * (size_t)N + gc];
      C[orow * (size_t)N + gc] = v;
    }
  }
}

// ---------------- RMSNorm (fp32 out, for final norm) ----------------
__global__ __launch_bounds__(256) void rmsnorm_k(
    const float* __restrict__ x, const float* __restrict__ w, float* __restrict__ out)
{
  __shared__ float lds[8];
  const int row = blockIdx.x;
  const float* xr = x + (size_t)row * Dd;
  float4 v = *(const float4*)&xr[threadIdx.x << 2];
  float ss = v.x * v.x + v.y * v.y + v.z * v.z + v.w * v.w;
  ss = block_reduce_sum(ss, lds);
  float sc = rsqrtf(ss * (1.f / Dd) + 1e-5f);
  float4 wv = *(const float4*)&w[threadIdx.x << 2];
  float4 o = {v.x * sc * wv.x, v.y * sc * wv.y, v.z * sc * wv.z, v.w * sc * wv.w};
  *(float4*)&out[(size_t)row * Dd + (threadIdx.x << 2)] = o;
}

// ---------------- RMSNorm (bf16 hi/lo out, feeds split GEMM) ----------------
__global__ __launch_bounds__(256) void rmsnorm2_k(
    const float* __restrict__ x, const float* __restrict__ w,
    unsigned short* __restrict__ oh, unsigned short* __restrict__ ol)
{
  __shared__ float lds[8];
  const int row = blockIdx.x;
  const float* xr = x + (size_t)row * Dd;
  float4 v = *(const float4*)&xr[threadIdx.x << 2];
  float ss = v.x * v.x + v.y * v.y + v.z * v.z + v.w * v.w;
  ss = block_reduce_sum(ss, lds);
  float sc = rsqrtf(ss * (1.f / Dd) + 1e-5f);
  float4 wv = *(const float4*)&w[threadIdx.x << 2];
  ushort4 h, l;
  split2(v.x * sc * wv.x, h.x, l.x);
  split2(v.y * sc * wv.y, h.y, l.y);
  split2(v.z * sc * wv.z, h.z, l.z);
  split2(v.w * sc * wv.w, h.w, l.w);
  size_t o = (size_t)row * Dd + (threadIdx.x << 2);
  *(ushort4*)&oh[o] = h;
  *(ushort4*)&ol[o] = l;
}

// ---------------- dt = softplus(proj_dt + bias), da = exp(dt*A) ----------------
__global__ void dtda_k(const float* __restrict__ proj, const float* __restrict__ dt_bias,
                       const float* __restrict__ A_log, float* __restrict__ dtb,
                       float* __restrict__ dab)
{
  int idx = blockIdx.x * 256 + threadIdx.x;
  if (idx >= Bb * Tt * HH) return;
  int row = idx >> 5;
  int h = idx & 31;
  float v = proj[(size_t)row * PROJP + 2 * DIi + 2 * NNs + h] + dt_bias[h];
  float dt = (v > 20.f) ? v : log1pf(expf(v));
  float A = -expf(A_log[h]);
  dtb[idx] = dt;
  dab[idx] = expf(dt * A);
}

// ---------------- SSD scan, depth-3 prefetch ring ----------------
// one wave owns (b, h, 4 p-rows); lane = p_local(4) x n-chunk(16 of 8)
__global__ __launch_bounds__(256) void scan_k(
    const float* __restrict__ proj, const float* __restrict__ dtb,
    const float* __restrict__ dab, const float* __restrict__ Dssm,
    float* __restrict__ ybuf)
{
  const int gw = blockIdx.x * 4 + (threadIdx.x >> 6);   // 0..2047
  const int lane = threadIdx.x & 63;
  const int pg = gw & 15;
  const int h = (gw >> 4) & 31;
  const int b = gw >> 9;
  const int p_local = lane & 3;
  const int chunk = lane >> 2;            // 0..15
  const int p = (pg << 2) + p_local;
  const int n0 = chunk << 3;
  const float Ds = Dssm[h];
  const float* prow = proj + (size_t)b * Tt * PROJP;
  const int xoff = DIi + h * PP + p;
  const int boff = 2 * DIi + n0;
  const int coff = 2 * DIi + NNs + n0;
  const int dbase = b * Tt * HH + h;

  float hs[8] = {0, 0, 0, 0, 0, 0, 0, 0};
  float up[8] = {0, 0, 0, 0, 0, 0, 0, 0};

  float4 sB0[3], sB1[3], sC0[3], sC1[3];
  float sx[3], sdt[3], sda[3];
#pragma unroll
  for (int s = 0; s < 3; s++) {
    const float* r = prow + (size_t)s * PROJP;
    sx[s]  = r[xoff];
    sB0[s] = *(const float4*)&r[boff];
    sB1[s] = *(const float4*)&r[boff + 4];
    sC0[s] = *(const float4*)&r[coff];
    sC1[s] = *(const float4*)&r[coff + 4];
    sdt[s] = dtb[dbase + s * HH];
    sda[s] = dab[dbase + s * HH];
  }

  for (int t = 0; t < Tt; t += 3) {
#pragma unroll
    for (int j = 0; j < 3; j++) {
      const int tc = t + j;
      // consume slot j
      float xv = sx[j], dtv = sdt[j], dav = sda[j];
      float Ba[8] = {sB0[j].x, sB0[j].y, sB0[j].z, sB0[j].w,
                     sB1[j].x, sB1[j].y, sB1[j].z, sB1[j].w};
      float Ca[8] = {sC0[j].x, sC0[j].y, sC0[j].z, sC0[j].w,
                     sC1[j].x, sC1[j].y, sC1[j].z, sC1[j].w};
      // refill slot j (row tc+3, clamped; clamped rows are never consumed)
      int tr = tc + 3; tr = (tr < Tt) ? tr : (Tt - 1);
      const float* r = prow + (size_t)tr * PROJP;
      sx[j]  = r[xoff];
      sB0[j] = *(const float4*)&r[boff];
      sB1[j] = *(const float4*)&r[boff + 4];
      sC0[j] = *(const float4*)&r[coff];
      sC1[j] = *(const float4*)&r[coff + 4];
      sdt[j] = dtb[dbase + tr * HH];
      sda[j] = dab[dbase + tr * HH];
      // compute step tc
      float dtx = dtv * xv;
      float s1 = 0.5f * dav;   // alpha*da
      float yp = 0.f;
#pragma unroll
      for (int e = 0; e < 8; e++) {
        float u = dtx * Ba[e];
        float inner = fmaf(s1, up[e], 0.5f * u);
        hs[e] = fmaf(dav, hs[e], inner);
        yp = fmaf(hs[e], Ca[e], yp);
        up[e] = u;
      }
      yp += __shfl_down(yp, 32, 64);
      yp += __shfl_down(yp, 16, 64);
      yp += __shfl_down(yp, 8, 64);
      yp += __shfl_down(yp, 4, 64);
      if (lane < 4) {
        ybuf[((size_t)b * Tt + tc) * DIi + h * PP + (pg << 2) + lane] = yp + Ds * xv;
      }
    }
  }
}

// ---------------- fused silu-gate + RMSNorm over DI=2048, bf16 hi/lo out ----------------
__global__ __launch_bounds__(256) void gate_norm2_k(
    const float* __restrict__ ybuf, const float* __restrict__ proj,
    const float* __restrict__ gw,
    unsigned short* __restrict__ yh, unsigned short* __restrict__ yl)
{
  __shared__ float lds[8];
  const int row = blockIdx.x;
  const float* yr = ybuf + (size_t)row * DIi;
  const float* zr = proj + (size_t)row * PROJP;   // z = cols [0, 2048)
  const int base = threadIdx.x << 3;
  float4 z0 = *(const float4*)&zr[base];
  float4 z1 = *(const float4*)&zr[base + 4];
  float4 y0 = *(const float4*)&yr[base];
  float4 y1 = *(const float4*)&yr[base + 4];
  float zz[8] = {z0.x, z0.y, z0.z, z0.w, z1.x, z1.y, z1.z, z1.w};
  float yy[8] = {y0.x, y0.y, y0.z, y0.w, y1.x, y1.y, y1.z, y1.w};
  float g[8];
  float ss = 0.f;
#pragma unroll
  for (int e = 0; e < 8; e++) {
    float s = zz[e] / (1.f + expf(-zz[e]));
    float gv = yy[e] * s;
    g[e] = gv;
    ss += gv * gv;
  }
  ss = block_reduce_sum(ss, lds);
  float sc = rsqrtf(ss * (1.f / DIi) + 1e-5f);
  ushort4 h0, l0, h1, l1;
  split2(g[0] * sc * gw[base + 0], h0.x, l0.x);
  split2(g[1] * sc * gw[base + 1], h0.y, l0.y);
  split2(g[2] * sc * gw[base + 2], h0.z, l0.z);
  split2(g[3] * sc * gw[base + 3], h0.w, l0.w);
  split2(g[4] * sc * gw[base + 4], h1.x, l1.x);
  split2(g[5] * sc * gw[base + 5], h1.y, l1.y);
  split2(g[6] * sc * gw[base + 6], h1.z, l1.z);
  split2(g[7] * sc * gw[base + 7], h1.w, l1.w);
  size_t o = (size_t)row * DIi + base;
  *(ushort4*)&yh[o] = h0; *(ushort4*)&yh[o + 4] = h1;
  *(ushort4*)&yl[o] = l0; *(ushort4*)&yl[o + 4] = l1;
}

// ---------------- mean over T ----------------
__global__ void pool_k(const float* __restrict__ xin, float* __restrict__ pooled) {
  int b = blockIdx.x;
  int d = blockIdx.y * 256 + threadIdx.x;
  const float* base = xin + (size_t)b * Tt * Dd + d;
  float s = 0.f;
  for (int t = 0; t < Tt; t++) s += base[(size_t)t * Dd];
  pooled[b * Dd + d] = s * (1.f / Tt);
}

// ---------------- L2-normalize rows of (4, 1536), in place ----------------
__global__ __launch_bounds__(256) void l2norm_k(float* __restrict__ out) {
  __shared__ float lds[8];
  const int row = blockIdx.x;
  float* r = out + (size_t)row * EE;
  float v[6];
  float ss = 0.f;
#pragma unroll
  for (int e = 0; e < 6; e++) {
    v[e] = r[(e << 8) + threadIdx.x];
    ss += v[e] * v[e];
  }
  ss = block_reduce_sum(ss, lds);
  float sc = 1.f / fmaxf(sqrtf(ss), 1e-12f);
#pragma unroll
  for (int e = 0; e < 6; e++) r[(e << 8) + threadIdx.x] = v[e] * sc;
}

// ---------------- launch ----------------
extern "C" void kernel_launch(void* const* d_in, const int* in_sizes, int n_in,
                              void* d_out, int out_size, void* d_ws, size_t ws_size,
                              hipStream_t stream) {
  (void)in_sizes; (void)n_in; (void)out_size; (void)ws_size;
  const float* visual   = (const float*)d_in[0];
  const float* query    = (const float*)d_in[1];
  const float* vis_w    = (const float*)d_in[2];
  const float* vis_b    = (const float*)d_in[3];
  const float* qry_w    = (const float*)d_in[4];
  const float* qry_b    = (const float*)d_in[5];
  const float* norm_ws  = (const float*)d_in[6];
  const float* in_ws    = (const float*)d_in[7];
  const float* dt_biases= (const float*)d_in[8];
  const float* A_logs   = (const float*)d_in[9];
  const float* D_ssm    = (const float*)d_in[10];
  const float* gnorm_ws = (const float*)d_in[11];
  const float* out_ws   = (const float*)d_in[12];
  const float* norm_f_w = (const float*)d_in[13];
  const float* head_w   = (const float*)d_in[14];
  const float* head_b   = (const float*)d_in[15];
  float* out = (float*)d_out;

  // workspace layout (bytes), all 16B-aligned; total ~67.6 MB
  char* w = (char*)d_ws;
  float*          hidden = (float*)w;          w += (size_t)1152 * 1024 * 4;
  unsigned short* xh     = (unsigned short*)w; w += (size_t)1152 * 1024 * 2;
  unsigned short* xl     = (unsigned short*)w; w += (size_t)1152 * 1024 * 2;
  float*          proj   = (float*)w;          w += (size_t)1152 * PROJP * 4;
  float*          ybuf   = (float*)w;          w += (size_t)1152 * 2048 * 4;
  unsigned short* yh     = (unsigned short*)w; w += (size_t)1152 * 2048 * 2;
  unsigned short* yl     = (unsigned short*)w; w += (size_t)1152 * 2048 * 2;
  float*          dtb    = (float*)w;          w += (size_t)36864 * 4;
  float*          dab    = (float*)w;          w += (size_t)36864 * 4;
  float*          pooled = (float*)w;          w += (size_t)4096 * 4;
  unsigned short* wth    = (unsigned short*)w; w += (size_t)PROJP * 1024 * 2;
  unsigned short* wtl    = (unsigned short*)w; w += (size_t)PROJP * 1024 * 2;

  dim3 blk(256);

  // ---- init projections (split-bf16 MFMA) ----
  cvt_act2_k<<<1024, blk, 0, stream>>>(visual, xh, xl, 1024 * 1024);
  cvt_act2_k<<<128, blk, 0, stream>>>(query, xh + (size_t)1024 * 1024,
                                      xl + (size_t)1024 * 1024, 128 * 1024);
  cvt_tr2_k<<<dim3(32, 32), blk, 0, stream>>>(vis_w, wth, wtl, 1024, 1024);
  gemm3_k<64, 64><<<dim3(16, 16), blk, 0, stream>>>(
      xh, xl, wth, wtl, vis_b, nullptr, hidden, 1024, 1024, 1024, 256, Tt, 0);
  cvt_tr2_k<<<dim3(32, 32), blk, 0, stream>>>(qry_w, wth, wtl, 1024, 1024);
  gemm3_k<64, 64><<<dim3(16, 2), blk, 0, stream>>>(
      xh + (size_t)1024 * 1024, xl + (size_t)1024 * 1024, wth, wtl,
      qry_b, nullptr, hidden, 128, 1024, 1024, 32, Tt, 256);

  for (int i = 0; i < NLl; i++) {
    rmsnorm2_k<<<Bb * Tt, blk, 0, stream>>>(hidden, norm_ws + i * Dd, xh, xl);
    // in-proj: W [1024][4384] -> Wt [4480][1024]; C = proj [1152][4480]
    cvt_tr2_k<<<dim3(PROJP / 32, 32), blk, 0, stream>>>(
        in_ws + (size_t)i * Dd * PROJ, wth, wtl, Dd, PROJ);
    gemm3_k<128, 128><<<dim3(PROJP / 128, 9), blk, 0, stream>>>(
        xh, xl, wth, wtl, nullptr, nullptr, proj, 1152, PROJP, Dd, 1152, 0, 0);
    dtda_k<<<144, blk, 0, stream>>>(proj, dt_biases + i * HH, A_logs + i * HH, dtb, dab);
    scan_k<<<512, blk, 0, stream>>>(proj, dtb, dab, D_ssm + i * HH, ybuf);
    gate_norm2_k<<<Bb * Tt, blk, 0, stream>>>(ybuf, proj, gnorm_ws + i * DIi, yh, yl);
    // out-proj: W [2048][1024] -> Wt [1024][2048]; C = hidden (+res)
    cvt_tr2_k<<<dim3(32, 64), blk, 0, stream>>>(
        out_ws + (size_t)i * DIi * Dd, wth, wtl, DIi, Dd);
    gemm3_k<64, 64><<<dim3(16, 18), blk, 0, stream>>>(
        yh, yl, wth, wtl, nullptr, hidden, hidden, 1152, Dd, DIi, 1152, 0, 0);
  }

  rmsnorm_k<<<Bb * Tt, blk, 0, stream>>>(hidden, norm_f_w, ybuf);
  pool_k<<<dim3(Bb, 4), blk, 0, stream>>>(ybuf, pooled);
  gemm_k<<<dim3(24, 1), blk, 0, stream>>>(pooled, head_w, head_b, nullptr, out,
                                          Bb, EE, Dd, Bb, 0, 0);
  l2norm_k<<<Bb, blk, 0, stream>>>(out);
}

// Round 4
// 2773.630 us; speedup vs baseline: 2.4100x; 1.2164x over previous
//
#include <hip/hip_runtime.h>
#include <cmath>

// Shapes (fixed by the problem)
#define Bb   4
#define Tt   288      // NV(256) + NQ(32)
#define Dd   1024
#define DIi  2048
#define HH   32
#define PP   64
#define NNs  128
#define PROJ  4384    // 2*DI + 2*N + H (logical)
#define PROJP 4480    // padded to 35*128 for MFMA tiles
#define NLl  12
#define EE   1536

typedef __bf16 bf16x8 __attribute__((ext_vector_type(8)));
typedef float f32x4 __attribute__((ext_vector_type(4)));

__device__ __forceinline__ unsigned short f2bf(float v) {
  __bf16 b = (__bf16)v;
  return __builtin_bit_cast(unsigned short, b);
}
__device__ __forceinline__ float bf2f(unsigned short u) {
  unsigned int x = ((unsigned int)u) << 16;
  return __builtin_bit_cast(float, x);
}
// split fp32 -> (hi, lo) bf16 pair: v ~= hi + lo to ~16 mantissa bits
__device__ __forceinline__ void split2(float v, unsigned short& h, unsigned short& l) {
  h = f2bf(v);
  l = f2bf(v - bf2f(h));
}

// async global->LDS, 16B per lane (lane-linear LDS layout required)
__device__ __forceinline__ void async16(const void* g, void* l) {
  __builtin_amdgcn_global_load_lds(
      (const __attribute__((address_space(1))) unsigned int*)g,
      (__attribute__((address_space(3))) unsigned int*)l, 16, 0, 0);
}

// ---------------- block reduction helper ----------------
__device__ inline float block_reduce_sum(float v, float* lds) {
#pragma unroll
  for (int d = 32; d > 0; d >>= 1) v += __shfl_down(v, d, 64);
  int lane = threadIdx.x & 63;
  int w = threadIdx.x >> 6;
  if (lane == 0) lds[w] = v;
  __syncthreads();
  if (threadIdx.x == 0) {
    float s = lds[0];
    int nw = blockDim.x >> 6;
    for (int i = 1; i < nw; i++) s += lds[i];
    lds[0] = s;
  }
  __syncthreads();
  return lds[0];
}

// ---------------- fp32 -> bf16 hi/lo (activations) ----------------
__global__ __launch_bounds__(256) void cvt_act2_k(const float* __restrict__ x,
                                                  unsigned short* __restrict__ oh,
                                                  unsigned short* __restrict__ ol, int n) {
  int idx = (blockIdx.x * 256 + threadIdx.x) * 4;
  if (idx >= n) return;
  float4 v = *(const float4*)&x[idx];
  ushort4 h, l;
  split2(v.x, h.x, l.x); split2(v.y, h.y, l.y);
  split2(v.z, h.z, l.z); split2(v.w, h.w, l.w);
  *(ushort4*)&oh[idx] = h;
  *(ushort4*)&ol[idx] = l;
}

// ---------------- W fp32 [K][N] -> Wt hi/lo bf16 [Npad][K] (transpose+split+pad) ----------------
__global__ __launch_bounds__(256) void cvt_tr2_k(const float* __restrict__ W,
                                                 unsigned short* __restrict__ Wth,
                                                 unsigned short* __restrict__ Wtl,
                                                 int K, int N) {
  __shared__ float tile[32][33];
  const int n0 = blockIdx.x * 32, k0 = blockIdx.y * 32;
  const int c = threadIdx.x & 31;
  const int r0 = threadIdx.x >> 5;   // 0..7
#pragma unroll
  for (int j = 0; j < 4; j++) {
    int r = r0 + j * 8;
    int n = n0 + c;
    tile[r][c] = (n < N) ? W[(size_t)(k0 + r) * N + n] : 0.f;
  }
  __syncthreads();
  const int nl = threadIdx.x >> 3;        // 0..31
  const int kl = (threadIdx.x & 7) * 4;   // 0..28
  ushort4 h, l;
  split2(tile[kl + 0][nl], h.x, l.x);
  split2(tile[kl + 1][nl], h.y, l.y);
  split2(tile[kl + 2][nl], h.z, l.z);
  split2(tile[kl + 3][nl], h.w, l.w);
  size_t o = (size_t)(n0 + nl) * K + k0 + kl;
  *(ushort4*)&Wth[o] = h;
  *(ushort4*)&Wtl[o] = l;
}

// ---------------- split-bf16 MFMA GEMM, B^T, 3-term (hi*hi + hi*lo + lo*hi) ----------------
template<int BM, int BN>
__global__ __launch_bounds__(256) void gemm3_k(
    const unsigned short* __restrict__ Ah, const unsigned short* __restrict__ Al,
    const unsigned short* __restrict__ Wh, const unsigned short* __restrict__ Wl,
    const float* __restrict__ bias, const float* __restrict__ res,
    float* __restrict__ C, int M, int N, int K,
    int rows_per_b, int T_total, int t_off)
{
  constexpr int FM = BM / 32;   // frags per wave (m)
  constexpr int FN = BN / 32;   // frags per wave (n)
  __shared__ __align__(16) unsigned short Ash[BM * 32];
  __shared__ __align__(16) unsigned short Asl[BM * 32];
  __shared__ __align__(16) unsigned short Bsh[BN * 32];
  __shared__ __align__(16) unsigned short Bsl[BN * 32];
  const int tid = threadIdx.x;
  const int lane = tid & 63;
  const int wm = (tid >> 6) >> 1;
  const int wn = (tid >> 6) & 1;
  const int m0 = blockIdx.y * BM;
  const int n0 = blockIdx.x * BN;
  const int lrow = lane & 15;
  const int lkb = (lane >> 4) * 8;   // k-element offset within tile

  f32x4 acc[FM][FN];
#pragma unroll
  for (int i = 0; i < FM; i++)
#pragma unroll
    for (int j = 0; j < FN; j++) acc[i][j] = (f32x4)0.0f;

  for (int k0 = 0; k0 < K; k0 += 32) {
#pragma unroll
    for (int c = 0; c < BM / 64; c++) {
      int o = (c * 256 + tid) * 16;    // byte offset (row-major [BM][32] bf16 = 64B/row)
      int row = o >> 6;
      int colb = o & 63;
      size_t gb = ((size_t)(m0 + row) * K + k0) * 2 + colb;
      async16((const char*)Ah + gb, (char*)Ash + o);
      async16((const char*)Al + gb, (char*)Asl + o);
    }
#pragma unroll
    for (int c = 0; c < BN / 64; c++) {
      int o = (c * 256 + tid) * 16;
      int row = o >> 6;
      int colb = o & 63;
      size_t gb = ((size_t)(n0 + row) * K + k0) * 2 + colb;
      async16((const char*)Wh + gb, (char*)Bsh + o);
      async16((const char*)Wl + gb, (char*)Bsl + o);
    }
    __syncthreads();   // drains vmcnt (global_load_lds) + barrier

    bf16x8 ah[FM], al[FM], bh[FN], bl[FN];
#pragma unroll
    for (int i = 0; i < FM; i++) {
      int off = (wm * (FM * 16) + i * 16 + lrow) * 32 + lkb;
      ah[i] = *(const bf16x8*)&Ash[off];
      al[i] = *(const bf16x8*)&Asl[off];
    }
#pragma unroll
    for (int j = 0; j < FN; j++) {
      int off = (wn * (FN * 16) + j * 16 + lrow) * 32 + lkb;
      bh[j] = *(const bf16x8*)&Bsh[off];
      bl[j] = *(const bf16x8*)&Bsl[off];
    }
#pragma unroll
    for (int i = 0; i < FM; i++)
#pragma unroll
      for (int j = 0; j < FN; j++) {
        acc[i][j] = __builtin_amdgcn_mfma_f32_16x16x32_bf16(ah[i], bh[j], acc[i][j], 0, 0, 0);
        acc[i][j] = __builtin_amdgcn_mfma_f32_16x16x32_bf16(ah[i], bl[j], acc[i][j], 0, 0, 0);
        acc[i][j] = __builtin_amdgcn_mfma_f32_16x16x32_bf16(al[i], bh[j], acc[i][j], 0, 0, 0);
      }
    __syncthreads();
  }

  const int erow = (lane >> 4) * 4;
#pragma unroll
  for (int i = 0; i < FM; i++) {
    int mbase = m0 + wm * (FM * 16) + i * 16 + erow;
#pragma unroll
    for (int j = 0; j < FN; j++) {
      int ncol = n0 + wn * (FN * 16) + j * 16 + lrow;
      float bv = bias ? bias[ncol] : 0.f;
#pragma unroll
      for (int e = 0; e < 4; e++) {
        int m = mbase + e;
        size_t orow;
        if (T_total) {
          int bbv = m / rows_per_b;
          orow = (size_t)bbv * T_total + (m - bbv * rows_per_b) + t_off;
        } else {
          orow = (size_t)m;
        }
        float v = acc[i][j][e] + bv;
        if (res) v += res[orow * N + ncol];
        C[orow * N + ncol] = v;
      }
    }
  }
}

// ---------------- general tiled fp32 GEMM (tiny head matmul only) ----------------
__global__ __launch_bounds__(256) void gemm_k(
    const float* __restrict__ A, const float* __restrict__ W,
    const float* __restrict__ bias, const float* __restrict__ res,
    float* __restrict__ C, int M, int N, int K,
    int rows_per_b, int T_total, int t_off)
{
  __shared__ float As[16][64];
  __shared__ float Ws[16][64];
  const int tid = threadIdx.x;
  const int tx = tid & 15;
  const int ty = tid >> 4;
  const int m0 = blockIdx.y * 64;
  const int n0 = blockIdx.x * 64;
  float acc[4][4] = {};
  const int ar = tid >> 2;
  const int ac = (tid & 3) << 2;
  const int wr = tid >> 4;
  const int wc = (tid & 15) << 2;

  for (int k0 = 0; k0 < K; k0 += 16) {
    float4 av = {0.f, 0.f, 0.f, 0.f};
    int gr = m0 + ar;
    if (gr < M) av = *(const float4*)&A[(size_t)gr * K + k0 + ac];
    As[ac + 0][ar] = av.x; As[ac + 1][ar] = av.y;
    As[ac + 2][ar] = av.z; As[ac + 3][ar] = av.w;

    float4 wv = {0.f, 0.f, 0.f, 0.f};
    int gc = n0 + wc;
    const float* wp = &W[(size_t)(k0 + wr) * N + gc];
    if (gc + 3 < N) {
      wv = *(const float4*)wp;
    } else {
      if (gc + 0 < N) wv.x = wp[0];
      if (gc + 1 < N) wv.y = wp[1];
      if (gc + 2 < N) wv.z = wp[2];
    }
    *(float4*)&Ws[wr][wc] = wv;
    __syncthreads();
#pragma unroll
    for (int kk = 0; kk < 16; kk++) {
      float4 a4 = *(const float4*)&As[kk][ty << 2];
      float4 b4 = *(const float4*)&Ws[kk][tx << 2];
      float a[4] = {a4.x, a4.y, a4.z, a4.w};
      float b[4] = {b4.x, b4.y, b4.z, b4.w};
#pragma unroll
      for (int i = 0; i < 4; i++)
#pragma unroll
        for (int j = 0; j < 4; j++)
          acc[i][j] = fmaf(a[i], b[j], acc[i][j]);
    }
    __syncthreads();
  }
#pragma unroll
  for (int i = 0; i < 4; i++) {
    int gr = m0 + (ty << 2) + i;
    if (gr >= M) continue;
    int bbv = gr / rows_per_b;
    int tt = gr - bbv * rows_per_b;
    size_t orow = (size_t)bbv * T_total + tt + t_off;
#pragma unroll
    for (int j = 0; j < 4; j++) {
      int gc = n0 + (tx << 2) + j;
      if (gc >= N) continue;
      float v = acc[i][j];
      if (bias) v += bias[gc];
      if (res)  v += res[orow * (size_t)N + gc];
      C[orow * (size_t)N + gc] = v;
    }
  }
}

// ---------------- RMSNorm (fp32 out, for final norm) ----------------
__global__ __launch_bounds__(256) void rmsnorm_k(
    const float* __restrict__ x, const float* __restrict__ w, float* __restrict__ out)
{
  __shared__ float lds[8];
  const int row = blockIdx.x;
  const float* xr = x + (size_t)row * Dd;
  float4 v = *(const float4*)&xr[threadIdx.x << 2];
  float ss = v.x * v.x + v.y * v.y + v.z * v.z + v.w * v.w;
  ss = block_reduce_sum(ss, lds);
  float sc = rsqrtf(ss * (1.f / Dd) + 1e-5f);
  float4 wv = *(const float4*)&w[threadIdx.x << 2];
  float4 o = {v.x * sc * wv.x, v.y * sc * wv.y, v.z * sc * wv.z, v.w * sc * wv.w};
  *(float4*)&out[(size_t)row * Dd + (threadIdx.x << 2)] = o;
}

// ---------------- RMSNorm (bf16 hi/lo out, feeds split GEMM) ----------------
__global__ __launch_bounds__(256) void rmsnorm2_k(
    const float* __restrict__ x, const float* __restrict__ w,
    unsigned short* __restrict__ oh, unsigned short* __restrict__ ol)
{
  __shared__ float lds[8];
  const int row = blockIdx.x;
  const float* xr = x + (size_t)row * Dd;
  float4 v = *(const float4*)&xr[threadIdx.x << 2];
  float ss = v.x * v.x + v.y * v.y + v.z * v.z + v.w * v.w;
  ss = block_reduce_sum(ss, lds);
  float sc = rsqrtf(ss * (1.f / Dd) + 1e-5f);
  float4 wv = *(const float4*)&w[threadIdx.x << 2];
  ushort4 h, l;
  split2(v.x * sc * wv.x, h.x, l.x);
  split2(v.y * sc * wv.y, h.y, l.y);
  split2(v.z * sc * wv.z, h.z, l.z);
  split2(v.w * sc * wv.w, h.w, l.w);
  size_t o = (size_t)row * Dd + (threadIdx.x << 2);
  *(ushort4*)&oh[o] = h;
  *(ushort4*)&ol[o] = l;
}

// ---------------- dt = softplus(.), cum = prefix-sum(dt*A) in fp64 ----------------
// one wave per (b,h); wave-level inclusive scan over 64-t chunks
__global__ __launch_bounds__(64) void dtcum_k(
    const float* __restrict__ proj, const float* __restrict__ dt_bias,
    const float* __restrict__ A_log,
    float* __restrict__ dtt, double* __restrict__ dcum)
{
  const int h = blockIdx.x & 31;
  const int b = blockIdx.x >> 5;
  const int lane = threadIdx.x;
  const float A = -expf(A_log[h]);
  const float bias = dt_bias[h];
  const int rowo = (b * HH + h) * Tt;
  double base = 0.0;
  for (int c = 0; c < (Tt + 63) / 64; c++) {
    int t = c * 64 + lane;
    float dt = 0.f;
    if (t < Tt) {
      float v = proj[(size_t)(b * Tt + t) * PROJP + 2 * DIi + 2 * NNs + h] + bias;
      dt = (v > 20.f) ? v : log1pf(expf(v));
    }
    double a = (double)(dt * A);
#pragma unroll
    for (int d = 1; d < 64; d <<= 1) {
      double o = __shfl_up(a, d, 64);
      if (lane >= d) a += o;
    }
    double cum = base + a;
    if (t < Tt) { dtt[rowo + t] = dt; dcum[rowo + t] = cum; }
    base = __shfl(cum, 63, 64);
  }
}

// ---------------- St[b][j][t] = B[b,j,:]·C[b,t,:] (32x32 tiles, causal only) ----------------
__global__ __launch_bounds__(256) void cbgemm_k(const float* __restrict__ proj,
                                                float* __restrict__ St)
{
  const int tI = blockIdx.x, jI = blockIdx.y, b = blockIdx.z;
  if (jI > tI) return;   // strictly-upper tiles never read
  __shared__ float Ct[32][130];   // stride 130: 2-way bank alias only (free)
  __shared__ float Bt[32][130];
  const int tid = threadIdx.x;
  const int r = tid >> 3;          // 0..31
  const int q = (tid & 7) * 16;    // 16 floats each
  const float* pb = proj + (size_t)b * Tt * PROJP;
  {
    const float* crow = pb + (size_t)(tI * 32 + r) * PROJP + 2 * DIi + NNs + q;
    const float* brow = pb + (size_t)(jI * 32 + r) * PROJP + 2 * DIi + q;
#pragma unroll
    for (int f = 0; f < 16; f += 4) {
      float4 c4 = *(const float4*)&crow[f];
      float4 b4 = *(const float4*)&brow[f];
      // float2 stores (rows are 8B-aligned, not 16B)
      *(float2*)&Ct[r][q + f]     = make_float2(c4.x, c4.y);
      *(float2*)&Ct[r][q + f + 2] = make_float2(c4.z, c4.w);
      *(float2*)&Bt[r][q + f]     = make_float2(b4.x, b4.y);
      *(float2*)&Bt[r][q + f + 2] = make_float2(b4.z, b4.w);
    }
  }
  __syncthreads();
  const int j_r = tid >> 3;        // 0..31
  const int t_c = (tid & 7) * 4;   // 0..28
  float acc[4] = {0.f, 0.f, 0.f, 0.f};
  for (int n = 0; n < NNs; n += 2) {
    float2 b2 = *(const float2*)&Bt[j_r][n];
#pragma unroll
    for (int k = 0; k < 4; k++) {
      float2 c2 = *(const float2*)&Ct[t_c + k][n];
      acc[k] = fmaf(b2.x, c2.x, acc[k]);
      acc[k] = fmaf(b2.y, c2.y, acc[k]);
    }
  }
  float* so = St + ((size_t)b * Tt + jI * 32 + j_r) * Tt + tI * 32 + t_c;
  *(float4*)so = make_float4(acc[0], acc[1], acc[2], acc[3]);
}

// ---------------- Y[b,t,h,:] = sum_j M(t,j) * X[b,j,h,:]  (causal, decay-scaled) ----------------
// M(t,j) = dt_j * S(t,j) * exp(cum_t - cum_j)  (j<t);  M(t,t) = 0.5*dt_t*S + Ds
// block = (t-tile of 32) x (h) x (b); thread = (t_l, 8 of 64 p)
__global__ __launch_bounds__(256) void ssd_y_k(
    const float* __restrict__ proj, const float* __restrict__ St,
    const float* __restrict__ dtt, const double* __restrict__ dcum,
    const float* __restrict__ Dssm, float* __restrict__ ybuf)
{
  const int tI = blockIdx.x;          // 0..8
  const int h  = blockIdx.y;
  const int b  = blockIdx.z;
  __shared__ __align__(16) float Xs[32][64];
  __shared__ __align__(16) float Ss[32][36];   // Ss[j][t], stride 36: conflict-free on t
  __shared__ double cjs[32];
  const int tid = threadIdx.x;
  const int t_l = tid & 31;
  const int pg  = tid >> 5;           // 0..7
  const int t0  = tI * 32;
  const int rowo = (b * HH + h) * Tt;
  const double ct = dcum[rowo + t0 + t_l];
  const float Ds = Dssm[h];
  const float* pb = proj + (size_t)b * Tt * PROJP;
  float y[8] = {0,0,0,0,0,0,0,0};
  const int sr = tid >> 3;            // staging row 0..31
  const int sq = tid & 7;

  for (int jI = 0; jI <= tI; jI++) {
    const int j0 = jI * 32;
    {   // X tile [32 j][64 p] from xss slice
      const float* xr = pb + (size_t)(j0 + sr) * PROJP + DIi + h * PP + sq * 8;
      *(float4*)&Xs[sr][sq * 8]     = *(const float4*)&xr[0];
      *(float4*)&Xs[sr][sq * 8 + 4] = *(const float4*)&xr[4];
    }
    {   // S^T tile scaled by dt_j
      const float* srow = St + ((size_t)b * Tt + j0 + sr) * Tt + t0 + sq * 4;
      float4 s4 = *(const float4*)srow;
      float dj = dtt[rowo + j0 + sr];
      s4.x *= dj; s4.y *= dj; s4.z *= dj; s4.w *= dj;
      *(float4*)&Ss[sr][sq * 4] = s4;
    }
    if (tid < 32) cjs[tid] = dcum[rowo + j0 + tid];
    __syncthreads();

    if (jI < tI) {
#pragma unroll 4
      for (int j = 0; j < 32; j++) {
        float d = (float)(ct - cjs[j]);
        float m = Ss[j][t_l] * expf(fminf(d, 0.f));
        const float* xp = &Xs[j][pg * 8];
        float4 a0 = *(const float4*)&xp[0];
        float4 a1 = *(const float4*)&xp[4];
        y[0] = fmaf(m, a0.x, y[0]); y[1] = fmaf(m, a0.y, y[1]);
        y[2] = fmaf(m, a0.z, y[2]); y[3] = fmaf(m, a0.w, y[3]);
        y[4] = fmaf(m, a1.x, y[4]); y[5] = fmaf(m, a1.y, y[5]);
        y[6] = fmaf(m, a1.z, y[6]); y[7] = fmaf(m, a1.w, y[7]);
      }
    } else {   // diagonal tile: causal mask + diagonal formula
      for (int j = 0; j < 32; j++) {
        float sv = Ss[j][t_l];
        float d = (float)(ct - cjs[j]);
        float m = sv * expf(fminf(d, 0.f));
        if (j == t_l) m = 0.5f * sv + Ds;
        if (j > t_l)  m = 0.f;
        const float* xp = &Xs[j][pg * 8];
        float4 a0 = *(const float4*)&xp[0];
        float4 a1 = *(const float4*)&xp[4];
        y[0] = fmaf(m, a0.x, y[0]); y[1] = fmaf(m, a0.y, y[1]);
        y[2] = fmaf(m, a0.z, y[2]); y[3] = fmaf(m, a0.w, y[3]);
        y[4] = fmaf(m, a1.x, y[4]); y[5] = fmaf(m, a1.y, y[5]);
        y[6] = fmaf(m, a1.z, y[6]); y[7] = fmaf(m, a1.w, y[7]);
      }
    }
    __syncthreads();
  }
  float* yo = &ybuf[(size_t)(b * Tt + t0 + t_l) * DIi + h * PP + pg * 8];
  *(float4*)&yo[0] = make_float4(y[0], y[1], y[2], y[3]);
  *(float4*)&yo[4] = make_float4(y[4], y[5], y[6], y[7]);
}

// ---------------- fused silu-gate + RMSNorm over DI=2048, bf16 hi/lo out ----------------
__global__ __launch_bounds__(256) void gate_norm2_k(
    const float* __restrict__ ybuf, const float* __restrict__ proj,
    const float* __restrict__ gw,
    unsigned short* __restrict__ yh, unsigned short* __restrict__ yl)
{
  __shared__ float lds[8];
  const int row = blockIdx.x;
  const float* yr = ybuf + (size_t)row * DIi;
  const float* zr = proj + (size_t)row * PROJP;   // z = cols [0, 2048)
  const int base = threadIdx.x << 3;
  float4 z0 = *(const float4*)&zr[base];
  float4 z1 = *(const float4*)&zr[base + 4];
  float4 y0 = *(const float4*)&yr[base];
  float4 y1 = *(const float4*)&yr[base + 4];
  float zz[8] = {z0.x, z0.y, z0.z, z0.w, z1.x, z1.y, z1.z, z1.w};
  float yy[8] = {y0.x, y0.y, y0.z, y0.w, y1.x, y1.y, y1.z, y1.w};
  float g[8];
  float ss = 0.f;
#pragma unroll
  for (int e = 0; e < 8; e++) {
    float s = zz[e] / (1.f + expf(-zz[e]));
    float gv = yy[e] * s;
    g[e] = gv;
    ss += gv * gv;
  }
  ss = block_reduce_sum(ss, lds);
  float sc = rsqrtf(ss * (1.f / DIi) + 1e-5f);
  ushort4 h0, l0, h1, l1;
  split2(g[0] * sc * gw[base + 0], h0.x, l0.x);
  split2(g[1] * sc * gw[base + 1], h0.y, l0.y);
  split2(g[2] * sc * gw[base + 2], h0.z, l0.z);
  split2(g[3] * sc * gw[base + 3], h0.w, l0.w);
  split2(g[4] * sc * gw[base + 4], h1.x, l1.x);
  split2(g[5] * sc * gw[base + 5], h1.y, l1.y);
  split2(g[6] * sc * gw[base + 6], h1.z, l1.z);
  split2(g[7] * sc * gw[base + 7], h1.w, l1.w);
  size_t o = (size_t)row * DIi + base;
  *(ushort4*)&yh[o] = h0; *(ushort4*)&yh[o + 4] = h1;
  *(ushort4*)&yl[o] = l0; *(ushort4*)&yl[o + 4] = l1;
}

// ---------------- mean over T ----------------
__global__ void pool_k(const float* __restrict__ xin, float* __restrict__ pooled) {
  int b = blockIdx.x;
  int d = blockIdx.y * 256 + threadIdx.x;
  const float* base = xin + (size_t)b * Tt * Dd + d;
  float s = 0.f;
  for (int t = 0; t < Tt; t++) s += base[(size_t)t * Dd];
  pooled[b * Dd + d] = s * (1.f / Tt);
}

// ---------------- L2-normalize rows of (4, 1536), in place ----------------
__global__ __launch_bounds__(256) void l2norm_k(float* __restrict__ out) {
  __shared__ float lds[8];
  const int row = blockIdx.x;
  float* r = out + (size_t)row * EE;
  float v[6];
  float ss = 0.f;
#pragma unroll
  for (int e = 0; e < 6; e++) {
    v[e] = r[(e << 8) + threadIdx.x];
    ss += v[e] * v[e];
  }
  ss = block_reduce_sum(ss, lds);
  float sc = 1.f / fmaxf(sqrtf(ss), 1e-12f);
#pragma unroll
  for (int e = 0; e < 6; e++) r[(e << 8) + threadIdx.x] = v[e] * sc;
}

// ---------------- launch ----------------
extern "C" void kernel_launch(void* const* d_in, const int* in_sizes, int n_in,
                              void* d_out, int out_size, void* d_ws, size_t ws_size,
                              hipStream_t stream) {
  (void)in_sizes; (void)n_in; (void)out_size; (void)ws_size;
  const float* visual   = (const float*)d_in[0];
  const float* query    = (const float*)d_in[1];
  const float* vis_w    = (const float*)d_in[2];
  const float* vis_b    = (const float*)d_in[3];
  const float* qry_w    = (const float*)d_in[4];
  const float* qry_b    = (const float*)d_in[5];
  const float* norm_ws  = (const float*)d_in[6];
  const float* in_ws    = (const float*)d_in[7];
  const float* dt_biases= (const float*)d_in[8];
  const float* A_logs   = (const float*)d_in[9];
  const float* D_ssm    = (const float*)d_in[10];
  const float* gnorm_ws = (const float*)d_in[11];
  const float* out_ws   = (const float*)d_in[12];
  const float* norm_f_w = (const float*)d_in[13];
  const float* head_w   = (const float*)d_in[14];
  const float* head_b   = (const float*)d_in[15];
  float* out = (float*)d_out;

  // workspace layout (bytes), all 16B-aligned; total ~69 MB
  char* w = (char*)d_ws;
  float*          hidden = (float*)w;          w += (size_t)1152 * 1024 * 4;
  unsigned short* xh     = (unsigned short*)w; w += (size_t)1152 * 1024 * 2;
  unsigned short* xl     = (unsigned short*)w; w += (size_t)1152 * 1024 * 2;
  float*          proj   = (float*)w;          w += (size_t)1152 * PROJP * 4;
  float*          ybuf   = (float*)w;          w += (size_t)1152 * 2048 * 4;
  unsigned short* yh     = (unsigned short*)w; w += (size_t)1152 * 2048 * 2;
  unsigned short* yl     = (unsigned short*)w; w += (size_t)1152 * 2048 * 2;
  float*          dtt    = (float*)w;          w += (size_t)Bb * HH * Tt * 4;
  double*         dcum   = (double*)w;         w += (size_t)Bb * HH * Tt * 8;
  float*          Stb    = (float*)w;          w += (size_t)Bb * Tt * Tt * 4;
  float*          pooled = (float*)w;          w += (size_t)4096 * 4;
  unsigned short* wth    = (unsigned short*)w; w += (size_t)PROJP * 1024 * 2;
  unsigned short* wtl    = (unsigned short*)w; w += (size_t)PROJP * 1024 * 2;

  dim3 blk(256);

  // ---- init projections (split-bf16 MFMA) ----
  cvt_act2_k<<<1024, blk, 0, stream>>>(visual, xh, xl, 1024 * 1024);
  cvt_act2_k<<<128, blk, 0, stream>>>(query, xh + (size_t)1024 * 1024,
                                      xl + (size_t)1024 * 1024, 128 * 1024);
  cvt_tr2_k<<<dim3(32, 32), blk, 0, stream>>>(vis_w, wth, wtl, 1024, 1024);
  gemm3_k<64, 64><<<dim3(16, 16), blk, 0, stream>>>(
      xh, xl, wth, wtl, vis_b, nullptr, hidden, 1024, 1024, 1024, 256, Tt, 0);
  cvt_tr2_k<<<dim3(32, 32), blk, 0, stream>>>(qry_w, wth, wtl, 1024, 1024);
  gemm3_k<64, 64><<<dim3(16, 2), blk, 0, stream>>>(
      xh + (size_t)1024 * 1024, xl + (size_t)1024 * 1024, wth, wtl,
      qry_b, nullptr, hidden, 128, 1024, 1024, 32, Tt, 256);

  for (int i = 0; i < NLl; i++) {
    rmsnorm2_k<<<Bb * Tt, blk, 0, stream>>>(hidden, norm_ws + i * Dd, xh, xl);
    // in-proj: W [1024][4384] -> Wt [4480][1024]; C = proj [1152][4480]
    cvt_tr2_k<<<dim3(PROJP / 32, 32), blk, 0, stream>>>(
        in_ws + (size_t)i * Dd * PROJ, wth, wtl, Dd, PROJ);
    gemm3_k<128, 128><<<dim3(PROJP / 128, 9), blk, 0, stream>>>(
        xh, xl, wth, wtl, nullptr, nullptr, proj, 1152, PROJP, Dd, 1152, 0, 0);
    // SSD quadratic form (replaces sequential scan)
    dtcum_k<<<Bb * HH, dim3(64), 0, stream>>>(proj, dt_biases + i * HH,
                                              A_logs + i * HH, dtt, dcum);
    cbgemm_k<<<dim3(9, 9, Bb), blk, 0, stream>>>(proj, Stb);
    ssd_y_k<<<dim3(9, HH, Bb), blk, 0, stream>>>(proj, Stb, dtt, dcum,
                                                 D_ssm + i * HH, ybuf);
    gate_norm2_k<<<Bb * Tt, blk, 0, stream>>>(ybuf, proj, gnorm_ws + i * DIi, yh, yl);
    // out-proj: W [2048][1024] -> Wt [1024][2048]; C = hidden (+res)
    cvt_tr2_k<<<dim3(32, 64), blk, 0, stream>>>(
        out_ws + (size_t)i * DIi * Dd, wth, wtl, DIi, Dd);
    gemm3_k<64, 64><<<dim3(16, 18), blk, 0, stream>>>(
        yh, yl, wth, wtl, nullptr, hidden, hidden, 1152, Dd, DIi, 1152, 0, 0);
  }

  rmsnorm_k<<<Bb * Tt, blk, 0, stream>>>(hidden, norm_f_w, ybuf);
  pool_k<<<dim3(Bb, 4), blk, 0, stream>>>(ybuf, pooled);
  gemm_k<<<dim3(24, 1), blk, 0, stream>>>(pooled, head_w, head_b, nullptr, out,
                                          Bb, EE, Dd, Bb, 0, 0);
  l2norm_k<<<Bb, blk, 0, stream>>>(out);
}